// Round 1
// 239.071 us; speedup vs baseline: 1.0655x; 1.0655x over previous
//
#include <hip/hip_runtime.h>
#include <hip/hip_fp16.h>

#define BB 2
#define AA 512
#define NN 1024
#define FF 64
#define DIN 128
#define DOUT 128
#define TH 25
#define ASTRIDE 40   // halves per a_tile row (16B-aligned frag base)
#define HSTRIDE 72   // halves per h_tile row (16B-aligned, 144B row pitch)
#define NSPLIT 4

typedef _Float16 half8 __attribute__((ext_vector_type(8)));
typedef _Float16 half4v __attribute__((ext_vector_type(4)));
typedef float floatx4 __attribute__((ext_vector_type(4)));

__device__ __forceinline__ float ssp_f(float x) {
    return __logf(0.5f * __expf(x) + 0.5f);  // softplus(x) - ln2
}

__device__ __forceinline__ float cutcos(float r) {
    float c = 0.5f * (__cosf(r * (3.14159265358979323846f / 5.0f)) + 1.0f);
    return (r < 5.0f) ? c : 0.0f;
}

// packed-f16 shifted softplus on a half2 (v_exp_f16/v_log_f16 + pk ops)
__device__ __forceinline__ __half2 ssp2(__half2 x) {
    const __half2 hlf = __float2half2_rn(0.5f);
    return h2log(__hfma2(h2exp(x), hlf, hlf));
}

// pack two f32 -> __half2 (v_cvt_pkrtz_f16_f32); bit-cast through memory
__device__ __forceinline__ __half2 pk2(float a, float b) {
    auto v = __builtin_amdgcn_cvt_pkrtz(a, b);  // __fp16 ext_vector(2)
    __half2 r;
    __builtin_memcpy(&r, &v, sizeof(r));
    return r;
}

// pack two half2 -> 4 x f16 for a single ds_write_b64
__device__ __forceinline__ half4v pack4(__half2 lo, __half2 hi) {
    half4v r;
    __builtin_memcpy(&r, &lo, 4);
    __builtin_memcpy(reinterpret_cast<char*>(&r) + 4, &hi, 4);
    return r;
}

// ---- d_ws layout (bytes) ----
#define OFF_Y       0                                              // 128 KB
#define OFF_PARTIAL (OFF_Y + (size_t)BB * AA * FF * 2)             // 1 MB
#define OFF_B1      (OFF_PARTIAL + (size_t)NSPLIT * BB * AA * FF * 4)
#define OFF_B2      (OFF_B1 + 4 * 64 * 8 * 2)
#define OFF_BP      (OFF_B2 + 8 * 64 * 8 * 2)                      // 4 KB bias pairs

// Kernel 1: in2f (all blocks) + weight-fragment prep (block 0 only).
__global__ void in2f_prep_kernel(const float* __restrict__ x,
                                 const float* __restrict__ Wi,
                                 _Float16* __restrict__ y,
                                 const float* __restrict__ W_t1, const float* __restrict__ b_t1,
                                 const float* __restrict__ W_t2, const float* __restrict__ b_t2,
                                 _Float16* __restrict__ B1tab, _Float16* __restrict__ B2tab,
                                 _Float16* __restrict__ BPtab) {
    __shared__ float xs[DIN];
    const int ba = blockIdx.x;
    const int t = threadIdx.x;  // 64
    xs[t] = x[ba * DIN + t];
    xs[t + 64] = x[ba * DIN + 64 + t];
    __syncthreads();
    float acc = 0.f;
#pragma unroll 8
    for (int d = 0; d < DIN; ++d) acc += xs[d] * Wi[d * FF + t];
    y[ba * FF + t] = (_Float16)acc;

    if (ba == 0) {  // prep: format MFMA fragments in per-lane layout
        const int lane = t, quad = t >> 4, l16 = t & 15;
#pragma unroll
        for (int g = 0; g < 4; ++g) {
#pragma unroll
            for (int j = 0; j < 8; ++j) {
                int k = quad * 8 + j;
                B1tab[(g * 64 + lane) * 8 + j] =
                    (k < TH) ? (_Float16)W_t1[k * FF + g * 16 + l16] : (_Float16)0.f;
            }
            // swapped-output bias pairs: lane (quad) holds features g*16+quad*4 .. +3
#pragma unroll
            for (int e = 0; e < 2; ++e) {
                BPtab[((g * 2 + e) * 64 + lane) * 2 + 0] =
                    (_Float16)b_t1[g * 16 + quad * 4 + 2 * e];
                BPtab[((g * 2 + e) * 64 + lane) * 2 + 1] =
                    (_Float16)b_t1[g * 16 + quad * 4 + 2 * e + 1];
                BPtab[1024 + ((g * 2 + e) * 64 + lane) * 2 + 0] =
                    (_Float16)b_t2[g * 16 + quad * 4 + 2 * e];
                BPtab[1024 + ((g * 2 + e) * 64 + lane) * 2 + 1] =
                    (_Float16)b_t2[g * 16 + quad * 4 + 2 * e + 1];
            }
#pragma unroll
            for (int q = 0; q < 2; ++q)
#pragma unroll
                for (int j = 0; j < 8; ++j)
                    B2tab[((g * 2 + q) * 64 + lane) * 8 + j] =
                        (_Float16)W_t2[(q * 32 + quad * 8 + j) * FF + g * 16 + l16];
        }
    }
}

// Kernel 2: per-(ba,split) partial of the triple MLP + gather/interp aggregation.
// NOTE: bare __launch_bounds__(256) — a (256,4) bound caps VGPRs at 64 and
// causes massive scratch spilling (measured: WRITE_SIZE 401 MB vs 1.5 MB legit).
__global__ __launch_bounds__(256) void triple_kernel(
    const int* __restrict__ nbrj, const int* __restrict__ nbrk,
    const float* __restrict__ r_ij, const float* __restrict__ r_ik,
    const float* __restrict__ tmask, const float* __restrict__ d_ijk,
    const _Float16* __restrict__ B1tab, const _Float16* __restrict__ B2tab,
    const _Float16* __restrict__ BPtab,
    const _Float16* __restrict__ y_tab, float* __restrict__ partial) {

    // per-wave buffers -> no __syncthreads in main loop (same-wave DS is in-order)
    __shared__ __align__(16) _Float16 a_tile[4][16 * ASTRIDE];
    __shared__ __align__(16) _Float16 h_tile[4][16 * HSTRIDE];  // h, then reused for filter
    __shared__ float red[4][FF];

    const int blk = blockIdx.x;
    const int ba = blk >> 2;
    const int split = blk & 3;
    const int b = ba >> 9;  // A = 512
    const int tid = threadIdx.x;
    const int w = tid >> 6;
    const int lane = tid & 63;
    const int quad = lane >> 4;
    const int l16 = lane & 15;
    const int rA = lane >> 3;        // row group: rows rA and rA+8
    const int fc = (lane & 7) * 8;   // feature chunk base (8 f16)

    const long ban = (long)ba * NN;
    const float* dbase = d_ijk + (long)ba * NN * TH;
    const _Float16* yb = y_tab + (long)b * (AA * FF);

    // ---- weight fragments: pre-formatted, 16 vector loads; bias pairs as half2 ----
    half8 B1[4];
    half8 B2[4][2];
    __half2 b1p[4][2], b2p[4][2];
#pragma unroll
    for (int g = 0; g < 4; ++g) {
        B1[g] = *(const half8*)(B1tab + (g * 64 + lane) * 8);
        B2[g][0] = *(const half8*)(B2tab + ((g * 2 + 0) * 64 + lane) * 8);
        B2[g][1] = *(const half8*)(B2tab + ((g * 2 + 1) * 64 + lane) * 8);
#pragma unroll
        for (int e = 0; e < 2; ++e) {
            b1p[g][e] = *(const __half2*)(BPtab + ((g * 2 + e) * 64 + lane) * 2);
            b2p[g][e] = *(const __half2*)(BPtab + 1024 + ((g * 2 + e) * 64 + lane) * 2);
        }
    }

    // ---- per-lane triple precompute: each lane owns ONE of this wave's 64 triples.
    //      Coalesced one-shot loads replace per-iteration broadcast HBM loads, and the
    //      cutoff/divide chain runs once instead of once-per-iteration x8 redundant lanes.
    const int myn = (split * 16 + quad * 4 + w) * 16 + l16;  // tile it=quad, row l16
    const long myna = ban + myn;
    const float rijL = r_ij[myna], rikL = r_ik[myna];
    const float ivL = cutcos(rijL) * cutcos(rikL) * tmask[myna] / (rijL + rikL);
    const float wjf = rijL * ivL, wkf = rikL * ivL;
    const int pjL = nbrj[myna], pkL = nbrk[myna];

    // zero A-tile K-pad cols 25..31 once
    for (int idx = lane; idx < 16 * 7; idx += 64) {
        int r = idx / 7, c = 25 + idx % 7;
        a_tile[w][r * ASTRIDE + c] = (_Float16)0.f;
    }

    // A staging map: 400 contiguous floats; 3 x float2/lane + 16-float tail
    int lofs2[3][2];
#pragma unroll
    for (int m = 0; m < 3; ++m)
#pragma unroll
        for (int e = 0; e < 2; ++e) {
            int s = m * 128 + lane * 2 + e;
            int r = s / TH, c = s - r * TH;
            lofs2[m][e] = r * ASTRIDE + c;
        }
    const int tofs = 15 * ASTRIDE + 9 + lane;  // tail: row 15 cols 9..24 (lane<16)

    float acc[8];
#pragma unroll
    for (int i = 0; i < 8; ++i) acc[i] = 0.f;
    const floatx4 zero4 = {0.f, 0.f, 0.f, 0.f};

    // ---- prologue: prefetch A tile for it=0 ----
    float2 pA[3];
    float pT = 0.f;
    {
        const int n0 = (split * 16 + w) * 16;
        const float* dsrc = dbase + n0 * TH;
#pragma unroll
        for (int m = 0; m < 3; ++m) pA[m] = *(const float2*)(dsrc + m * 128 + lane * 2);
        if (lane < 16) pT = dsrc[384 + lane];
    }

#pragma unroll 1
    for (int it = 0; it < NN / (16 * 4 * NSPLIT); ++it) {
        // 1. indices via cross-lane broadcast; issue gathers immediately
        const int sl0 = it * 16 + rA;   // lane holding triple n0+rA
        const int sl1 = sl0 + 8;        // lane holding triple n0+rA+8
        const int pj0 = __shfl(pjL, sl0), pk0 = __shfl(pkL, sl0);
        const int pj1 = __shfl(pjL, sl1), pk1 = __shfl(pkL, sl1);
        half8 gj0 = *(const half8*)(yb + pj0 * FF + fc);
        half8 gk0 = *(const half8*)(yb + pk0 * FF + fc);
        half8 gj1 = *(const half8*)(yb + pj1 * FF + fc);
        half8 gk1 = *(const half8*)(yb + pk1 * FF + fc);

        // 2. commit prefetched A -> LDS (f32 -> f16)
#pragma unroll
        for (int m = 0; m < 3; ++m) {
            a_tile[w][lofs2[m][0]] = (_Float16)pA[m].x;
            a_tile[w][lofs2[m][1]] = (_Float16)pA[m].y;
        }
        if (lane < 16) a_tile[w][tofs] = (_Float16)pT;

        // 3. prefetch next A tile (overlaps MFMA/ssp chain)
        if (it + 1 < NN / (16 * 4 * NSPLIT)) {
            const int n0 = (split * 16 + (it + 1) * 4 + w) * 16;
            const float* dn = dbase + n0 * TH;
#pragma unroll
            for (int m = 0; m < 3; ++m) pA[m] = *(const float2*)(dn + m * 128 + lane * 2);
            if (lane < 16) pT = dn[384 + lane];
        }

        // interp weights for this tile's two row-groups (4 shfl + 4 splats)
        const __half2 wj0 = __float2half2_rn(__shfl(wjf, sl0));
        const __half2 wk0 = __float2half2_rn(__shfl(wkf, sl0));
        const __half2 wj1 = __float2half2_rn(__shfl(wjf, sl1));
        const __half2 wk1 = __float2half2_rn(__shfl(wkf, sl1));

        // 4. matmul1 with SWAPPED operands: D[f][triple] (col = triple = l16,
        //    row = f = g*16+quad*4+r). Lane's 4 outputs are consecutive features of
        //    one triple -> single ds_write_b64 into h_tile[triple][f].
        half8 afrag = *(const half8*)&a_tile[w][l16 * ASTRIDE + quad * 8];
#pragma unroll
        for (int g = 0; g < 4; ++g) {
            floatx4 hv = __builtin_amdgcn_mfma_f32_16x16x32_f16(B1[g], afrag, zero4, 0, 0, 0);
            __half2 h01 = ssp2(__hadd2(pk2(hv[0], hv[1]), b1p[g][0]));
            __half2 h23 = ssp2(__hadd2(pk2(hv[2], hv[3]), b1p[g][1]));
            *(half4v*)&h_tile[w][l16 * HSTRIDE + g * 16 + quad * 4] = pack4(h01, h23);
        }

        // 5. matmul2 (K=64, swapped); filter written back into h_tile
        //    (safe: per-wave DS program order), read back in gather layout
        half8 a2q0 = *(const half8*)&h_tile[w][l16 * HSTRIDE + quad * 8];
        half8 a2q1 = *(const half8*)&h_tile[w][l16 * HSTRIDE + 32 + quad * 8];
#pragma unroll
        for (int g = 0; g < 4; ++g) {
            floatx4 w2 = __builtin_amdgcn_mfma_f32_16x16x32_f16(B2[g][0], a2q0, zero4, 0, 0, 0);
            w2 = __builtin_amdgcn_mfma_f32_16x16x32_f16(B2[g][1], a2q1, w2, 0, 0, 0);
            __half2 f01 = __hadd2(pk2(w2[0], w2[1]), b2p[g][0]);
            __half2 f23 = __hadd2(pk2(w2[2], w2[3]), b2p[g][1]);
            *(half4v*)&h_tile[w][l16 * HSTRIDE + g * 16 + quad * 4] = pack4(f01, f23);
        }
        half8 f0 = *(const half8*)&h_tile[w][rA * HSTRIDE + fc];
        half8 f1 = *(const half8*)&h_tile[w][(8 + rA) * HSTRIDE + fc];

        // 6. epilogue: packed-f16 interp + filter-mul (2 terms only in f16),
        //    flushed to f32 accumulators every iteration
        const __half2* gj0p = (const __half2*)&gj0;
        const __half2* gk0p = (const __half2*)&gk0;
        const __half2* gj1p = (const __half2*)&gj1;
        const __half2* gk1p = (const __half2*)&gk1;
        const __half2* f0p = (const __half2*)&f0;
        const __half2* f1p = (const __half2*)&f1;
#pragma unroll
        for (int p = 0; p < 4; ++p) {
            __half2 fv0 = __hfma2(wj0, gj0p[p], __hmul2(wk0, gk0p[p]));
            __half2 fv1 = __hfma2(wj1, gj1p[p], __hmul2(wk1, gk1p[p]));
            __half2 tot = __hfma2(f1p[p], fv1, __hmul2(f0p[p], fv0));
            acc[2 * p]     += __low2float(tot);
            acc[2 * p + 1] += __high2float(tot);
        }
    }

    // ---- reduce over row-groups within wave ----
#pragma unroll
    for (int i = 0; i < 8; ++i) {
        acc[i] += __shfl_xor(acc[i], 8, 64);
        acc[i] += __shfl_xor(acc[i], 16, 64);
        acc[i] += __shfl_xor(acc[i], 32, 64);
    }
    if (lane < 8)
#pragma unroll
        for (int i = 0; i < 8; ++i) red[w][lane * 8 + i] = acc[i];
    __syncthreads();

    if (tid < FF)
        partial[(split * (BB * AA) + ba) * FF + tid] =
            red[0][tid] + red[1][tid] + red[2][tid] + red[3][tid];
}

// Kernel 3: sum the NSPLIT partials, f2out matvec + ssp
__global__ void out_kernel(const float* __restrict__ partial,
                           const float* __restrict__ Wf,
                           const float* __restrict__ bf,
                           float* __restrict__ out) {
    __shared__ float yag[FF];
    const int ba = blockIdx.x;
    const int t = threadIdx.x;  // 128
    if (t < FF) {
        float s = 0.f;
#pragma unroll
        for (int sp = 0; sp < NSPLIT; ++sp)
            s += partial[(sp * (BB * AA) + ba) * FF + t];
        yag[t] = s;
    }
    __syncthreads();
    float a = bf[t];
#pragma unroll 8
    for (int f = 0; f < FF; ++f) a += yag[f] * Wf[f * DOUT + t];
    out[(long)ba * DOUT + t] = ssp_f(a);
}

extern "C" void kernel_launch(void* const* d_in, const int* in_sizes, int n_in,
                              void* d_out, int out_size, void* d_ws, size_t ws_size,
                              hipStream_t stream) {
    const float* x       = (const float*)d_in[0];
    const float* r_ij    = (const float*)d_in[2];
    const float* r_ik    = (const float*)d_in[3];
    const int*   nbrj    = (const int*)d_in[7];
    const int*   nbrk    = (const int*)d_in[8];
    const float* tmask   = (const float*)d_in[9];
    const float* d_ijk   = (const float*)d_in[10];
    const float* W_in2f  = (const float*)d_in[11];
    const float* W_t1    = (const float*)d_in[12];
    const float* b_t1    = (const float*)d_in[13];
    const float* W_t2    = (const float*)d_in[14];
    const float* b_t2    = (const float*)d_in[15];
    const float* W_f2out = (const float*)d_in[16];
    const float* b_f2out = (const float*)d_in[17];
    float* out = (float*)d_out;

    char* ws = (char*)d_ws;
    _Float16* y      = (_Float16*)(ws + OFF_Y);
    float* partial   = (float*)(ws + OFF_PARTIAL);
    _Float16* B1tab  = (_Float16*)(ws + OFF_B1);
    _Float16* B2tab  = (_Float16*)(ws + OFF_B2);
    _Float16* BPtab  = (_Float16*)(ws + OFF_BP);

    in2f_prep_kernel<<<BB * AA, 64, 0, stream>>>(x, W_in2f, y, W_t1, b_t1,
                                                 W_t2, b_t2, B1tab, B2tab, BPtab);
    triple_kernel<<<BB * AA * NSPLIT, 256, 0, stream>>>(nbrj, nbrk, r_ij, r_ik,
                                                        tmask, d_ijk, B1tab, B2tab,
                                                        BPtab, y, partial);
    out_kernel<<<BB * AA, 128, 0, stream>>>(partial, W_f2out, b_f2out, out);
}